// Round 4
// baseline (815.539 us; speedup 1.0000x reference)
//
#include <hip/hip_runtime.h>
#include <cstdint>
#include <cstddef>

typedef unsigned short u16;
typedef short bf16x8 __attribute__((ext_vector_type(8)));
typedef float f32x4 __attribute__((ext_vector_type(4)));

#define HIDDEN 4096
#define NH 32
#define NKV 8
#define HD 128
#define SEQL 2048
#define BATCH 2
#define NTOK (BATCH*SEQL)          /* 4096 tokens */
#define QKVN (HIDDEN + 2*NKV*HD)   /* 6144 */

#define QKS 68    /* padded LDS row stride (u16) for Ps */

__device__ __forceinline__ u16 f2bf(float f){
    unsigned u = __float_as_uint(f);
    u += 0x7FFF + ((u >> 16) & 1);   // RNE
    return (u16)(u >> 16);
}
__device__ __forceinline__ float bf2f(u16 h){
    return __uint_as_float(((unsigned)h) << 16);
}
__device__ __forceinline__ f32x4 zero4(){
    f32x4 z; z[0]=0.f; z[1]=0.f; z[2]=0.f; z[3]=0.f; return z;
}

typedef const unsigned int __attribute__((address_space(1)))* gas1_t;
typedef unsigned int __attribute__((address_space(3)))* las3_t;
__device__ __forceinline__ void gload_lds16(const u16* g, u16* l){
    __builtin_amdgcn_global_load_lds((gas1_t)g, (las3_t)l, 16, 0, 0);
}

// ---------------- f32 -> bf16 conversion (vectorized x4) ----------------
__global__ __launch_bounds__(256) void cvt_kernel(const float* __restrict__ src,
                                                  u16* __restrict__ dst, int n4){
    int i = blockIdx.x * 256 + threadIdx.x;
    if (i < n4){
        float4 v = ((const float4*)src)[i];
        ushort4 o;
        o.x = f2bf(v.x); o.y = f2bf(v.y); o.z = f2bf(v.z); o.w = f2bf(v.w);
        ((ushort4*)dst)[i] = o;
    }
}

// ---------------- GEMM 128x128: zero-tail variant for the QKV projection ----------------
// C[m,n] = sum_k A[m,k]*B[n,k]. 128x128 tile, BK=64, 4 waves (2Mx2N), 2 phases/K-tile,
// counted vmcnt. LDS 64 KiB -> 2 blocks/CU -> 1536 blocks on 512 slots = exactly 3
// generations (zero quantization tail, vs 384/256 = 1.5 -> 2 gens for the 256^2 kernel).
// Same swizzle algebra as gemm8_bt: row = 8 chunks of 16B, chunk c stored at slot
// c^(r&7); DMA dest linear, global source pre-swizzled; ds_read applies the XOR.
// Stage schedule per K-tile t (4 gloads per thread per mat):
//   p0: A(t+1) -> buf[(t+1)&1].A (dead since t-top barrier)
//   p1: B(t+2) -> buf[t&1].B     (B read only in p0; dead after p0 end barrier)
// Tile-top: vmcnt(4) leaves B(t+1)'s 4 loads in flight; drain-0 only on last tile.
template<int OUT_BF16>
__global__ __launch_bounds__(256) void gemm4_bt(const u16* __restrict__ A,
                                                const u16* __restrict__ B,
                                                void* __restrict__ Cp,
                                                int M, int N, int K){
    __shared__ __align__(16) u16 L[2][2][128*64];
    int tid = threadIdx.x;
    int wave = tid >> 6, lane = tid & 63, quad = lane >> 4, l16 = lane & 15;
    int wm = wave >> 1, wn = wave & 1;

    // XCD-aware block swizzle (grid % 8 == 0 at call sites)
    int nwg = gridDim.x;
    int cpx = nwg >> 3;
    int orig = blockIdx.x;
    int wg = (orig & 7) * cpx + (orig >> 3);
    int nbx = N >> 7;
    int bx = wg % nbx, by = wg / nbx;
    size_t row0 = (size_t)by * 128, col0 = (size_t)bx * 128;

    // staging: dest chunk (r = tid>>3, s = tid&7) pulls global chunk cc = s ^ (r&7);
    // sweeps j add 32 rows (r&7 invariant).
    int r0 = tid >> 3, cc = (tid & 7) ^ (r0 & 7);
    const u16* aS0 = A + (row0 + r0) * (size_t)K + cc * 8;
    const u16* bS0 = B + (col0 + r0) * (size_t)K + cc * 8;
    u16* ldsd = &L[0][0][0] + tid * 8;

#define STAGE_MAT(mat, bufi, kt) do {                                               \
        const u16* g_ = ((mat) ? bS0 : aS0) + (size_t)(kt) * 64;                    \
        u16* d_ = ldsd + (bufi)*16384 + (mat)*8192;                                 \
        gload_lds16(g_,                       d_);                                  \
        gload_lds16(g_ + (size_t)32 * K,      d_ + 2048);                           \
        gload_lds16(g_ + (size_t)64 * K,      d_ + 4096);                           \
        gload_lds16(g_ + (size_t)96 * K,      d_ + 6144);                           \
    } while(0)

    const int nt = K >> 6;

    // fragment read swizzle (r&7 == l16&7 for all fragment rows)
    int swz0 = ((0*4 + quad) ^ (l16 & 7)) * 8;
    int swz1 = ((1*4 + quad) ^ (l16 & 7)) * 8;

    f32x4 acc[4][4];
    #pragma unroll
    for (int i=0;i<4;i++)
        #pragma unroll
        for (int j=0;j<4;j++) acc[i][j] = zero4();

    // prologue: B(0), A(0) (oldest 8 loads), then B(1) (4 more in flight)
    STAGE_MAT(1, 0, 0);
    STAGE_MAT(0, 0, 0);
    STAGE_MAT(1, 1, 1);

    bf16x8 bF[4][2];
    for (int t = 0; t < nt; ++t){
        if (t < nt - 1) asm volatile("s_waitcnt vmcnt(4)" ::: "memory");
        else            asm volatile("s_waitcnt vmcnt(0)" ::: "memory");
        __builtin_amdgcn_s_barrier();
        const u16* bufA = &L[t & 1][0][0];
        const u16* bufB = &L[t & 1][1][0];

        #pragma unroll
        for (int p = 0; p < 2; ++p){
            bf16x8 aF[2][2];
            if (p == 0){
                #pragma unroll
                for (int ni = 0; ni < 4; ++ni){
                    int rb = (wn*64 + ni*16 + l16) * 64;
                    bF[ni][0] = *(const bf16x8*)(bufB + rb + swz0);
                    bF[ni][1] = *(const bf16x8*)(bufB + rb + swz1);
                }
            }
            #pragma unroll
            for (int i = 0; i < 2; ++i){
                int ra = (wm*64 + p*32 + i*16 + l16) * 64;
                aF[i][0] = *(const bf16x8*)(bufA + ra + swz0);
                aF[i][1] = *(const bf16x8*)(bufA + ra + swz1);
            }
            if (p == 0){ if (t + 1 < nt) STAGE_MAT(0, (t+1)&1, t+1); }
            if (p == 1){ if (t + 2 < nt) STAGE_MAT(1, t&1, t+2); }

            __builtin_amdgcn_sched_barrier(0);
            __builtin_amdgcn_s_barrier();
            __builtin_amdgcn_sched_barrier(0);
            __builtin_amdgcn_s_setprio(1);
            #pragma unroll
            for (int ni = 0; ni < 4; ++ni)
                #pragma unroll
                for (int i = 0; i < 2; ++i){
                    acc[p*2+i][ni] = __builtin_amdgcn_mfma_f32_16x16x32_bf16(aF[i][0], bF[ni][0], acc[p*2+i][ni], 0, 0, 0);
                    acc[p*2+i][ni] = __builtin_amdgcn_mfma_f32_16x16x32_bf16(aF[i][1], bF[ni][1], acc[p*2+i][ni], 0, 0, 0);
                }
            __builtin_amdgcn_s_setprio(0);
            __builtin_amdgcn_sched_barrier(0);
            asm volatile("s_waitcnt lgkmcnt(0)" ::: "memory");
            if (p == 0) __builtin_amdgcn_s_barrier();
        }
    }
#undef STAGE_MAT

    #pragma unroll
    for (int mi = 0; mi < 4; ++mi)
        #pragma unroll
        for (int ni = 0; ni < 4; ++ni){
            size_t row = row0 + wm*64 + mi*16 + quad*4;
            size_t col = col0 + wn*64 + ni*16 + l16;
            #pragma unroll
            for (int r = 0; r < 4; ++r){
                if (OUT_BF16) ((u16*)Cp)[(row + r) * (size_t)N + col] = f2bf(acc[mi][ni][r]);
                else          ((float*)Cp)[(row + r) * (size_t)N + col] = acc[mi][ni][r];
            }
        }
}

// ---------------- GEMM 256x256 (8-wave, 4-phase): kept for the O-projection ----------------
// 256 blocks = exactly one generation at 1 block/CU -> no tail; unchanged from round 1.
template<int OUT_BF16>
__global__ __launch_bounds__(512) void gemm8_bt(const u16* __restrict__ A,
                                                const u16* __restrict__ B,
                                                void* __restrict__ Cp,
                                                int M, int N, int K){
    __shared__ __align__(16) u16 L[2][2][256*64];
    int tid = threadIdx.x;
    int wave = tid >> 6, lane = tid & 63, quad = lane >> 4, l16 = lane & 15;
    int wm = wave >> 2, wn = wave & 3;

    int nwg = gridDim.x;
    int cpx = nwg >> 3;
    int orig = blockIdx.x;
    int wg = (orig & 7) * cpx + (orig >> 3);
    int nbx = N >> 8;
    int bx = wg % nbx, by = wg / nbx;
    size_t row0 = (size_t)by * 256, col0 = (size_t)bx * 256;

    int r0 = tid >> 3, cc = (tid & 7) ^ (r0 & 7);
    const u16* aS0 = A + (row0 + r0) * (size_t)K + cc * 8;
    const u16* bS0 = B + (col0 + r0) * (size_t)K + cc * 8;
    u16* ldsd = &L[0][0][0] + tid * 8;

#define STAGE_HALF(mat, half, bufi, kt) do {                                        \
        const u16* g_ = ((mat) ? bS0 : aS0) + (size_t)((half)*128) * K + (size_t)(kt) * 64; \
        u16* d_ = ldsd + (bufi)*32768 + (mat)*16384 + (half)*8192;                  \
        gload_lds16(g_, d_);                                                        \
        gload_lds16(g_ + (size_t)64 * K, d_ + 4096);                                \
    } while(0)

    const int nt = K >> 6;

    int swz0 = ((0*4 + quad) ^ (l16 & 7)) * 8;
    int swz1 = ((1*4 + quad) ^ (l16 & 7)) * 8;

    f32x4 acc[8][4];
    #pragma unroll
    for (int i=0;i<8;i++)
        #pragma unroll
        for (int j=0;j<4;j++) acc[i][j] = zero4();

    STAGE_HALF(1,0,0,0); STAGE_HALF(1,1,0,0);
    STAGE_HALF(0,0,0,0); STAGE_HALF(0,1,0,0);
    STAGE_HALF(1,0,1,1); STAGE_HALF(1,1,1,1);

    bf16x8 bF[4][2];
    for (int t = 0; t < nt; ++t){
        if (t < nt - 1) asm volatile("s_waitcnt vmcnt(4)" ::: "memory");
        else            asm volatile("s_waitcnt vmcnt(0)" ::: "memory");
        __builtin_amdgcn_s_barrier();
        const u16* bufA = &L[t & 1][0][0];
        const u16* bufB = &L[t & 1][1][0];

        #pragma unroll
        for (int p = 0; p < 4; ++p){
            bf16x8 aF[2][2];
            if (p == 0){
                #pragma unroll
                for (int ni = 0; ni < 4; ++ni){
                    int rb = (wn*64 + ni*16 + l16) * 64;
                    bF[ni][0] = *(const bf16x8*)(bufB + rb + swz0);
                    bF[ni][1] = *(const bf16x8*)(bufB + rb + swz1);
                }
            }
            #pragma unroll
            for (int i = 0; i < 2; ++i){
                int ra = (wm*128 + p*32 + i*16 + l16) * 64;
                aF[i][0] = *(const bf16x8*)(bufA + ra + swz0);
                aF[i][1] = *(const bf16x8*)(bufA + ra + swz1);
            }
            if (p == 0){ if (t + 1 < nt) STAGE_HALF(0, 0, (t+1)&1, t+1); }
            if (p == 1){ if (t + 1 < nt) STAGE_HALF(0, 1, (t+1)&1, t+1); }
            if (p == 2){ if (t + 2 < nt) STAGE_HALF(1, 0, t&1, t+2); }
            if (p == 3){ if (t + 2 < nt) STAGE_HALF(1, 1, t&1, t+2); }

            __builtin_amdgcn_sched_barrier(0);
            __builtin_amdgcn_s_barrier();
            __builtin_amdgcn_sched_barrier(0);
            __builtin_amdgcn_s_setprio(1);
            #pragma unroll
            for (int ni = 0; ni < 4; ++ni)
                #pragma unroll
                for (int i = 0; i < 2; ++i){
                    acc[p*2+i][ni] = __builtin_amdgcn_mfma_f32_16x16x32_bf16(aF[i][0], bF[ni][0], acc[p*2+i][ni], 0, 0, 0);
                    acc[p*2+i][ni] = __builtin_amdgcn_mfma_f32_16x16x32_bf16(aF[i][1], bF[ni][1], acc[p*2+i][ni], 0, 0, 0);
                }
            __builtin_amdgcn_s_setprio(0);
            __builtin_amdgcn_sched_barrier(0);
            asm volatile("s_waitcnt lgkmcnt(0)" ::: "memory");
            if (p < 3) __builtin_amdgcn_s_barrier();
        }
    }
#undef STAGE_HALF

    #pragma unroll
    for (int mi = 0; mi < 8; ++mi)
        #pragma unroll
        for (int ni = 0; ni < 4; ++ni){
            size_t row = row0 + wm*128 + mi*16 + quad*4;
            size_t col = col0 + wn*64 + ni*16 + l16;
            #pragma unroll
            for (int r = 0; r < 4; ++r){
                if (OUT_BF16) ((u16*)Cp)[(row + r) * (size_t)N + col] = f2bf(acc[mi][ni][r]);
                else          ((float*)Cp)[(row + r) * (size_t)N + col] = acc[mi][ni][r];
            }
        }
}

// ---------------- RoPE (in-place on QKV, Q+K regions only) ----------------
__global__ __launch_bounds__(256) void rope_kernel(u16* __restrict__ qkv,
                                                   const int* __restrict__ pos_ids){
    int idx = blockIdx.x * 256 + threadIdx.x;
    if (idx < 8388608){
        int tok = idx >> 11;
        int rem = idx & 2047;
        int h = rem >> 6, d = rem & 63;
        size_t base = (size_t)tok * QKVN + h * 128 + d;
        float v1 = bf2f(qkv[base]), v2 = bf2f(qkv[base + 64]);
        float p = (float)pos_ids[tok];
        float invf = exp2f((float)d * -0.2076205059304601f);  // 10000^(-d/64)
        float fr = p * invf;
        float s, c; __sincosf(fr, &s, &c);
        qkv[base]      = f2bf(v1 * c - v2 * s);
        qkv[base + 64] = f2bf(v2 * c + v1 * s);
    } else {
        int i2 = idx - 8388608;
        int tok = i2 >> 9;
        int rem = i2 & 511;
        int kv = rem >> 6, d = rem & 63;
        size_t base = (size_t)tok * QKVN + HIDDEN + kv * 128 + d;
        float v1 = bf2f(qkv[base]), v2 = bf2f(qkv[base + 64]);
        float p = (float)pos_ids[tok];
        float invf = exp2f((float)d * -0.2076205059304601f);
        float fr = p * invf;
        float s, c; __sincosf(fr, &s, &c);
        qkv[base]      = f2bf(v1 * c - v2 * s);
        qkv[base + 64] = f2bf(v2 * c + v1 * s);
    }
}

// ---------------- V transpose: [tok][kv][d] -> Vt[b,kv][d][tok] ----------------
__global__ __launch_bounds__(256) void vtrans_kernel(const u16* __restrict__ qkv,
                                                     u16* __restrict__ Vt){
    int blk = blockIdx.x;            // 512 blocks: (b,kv) x 32 token tiles
    int tt = blk & 31, bkv = blk >> 5;
    int b = bkv >> 3, kv = bkv & 7;
    const u16* src = qkv + (size_t)(b * SEQL + tt * 64) * QKVN + 5120 + kv * HD;
    u16* dst = Vt + ((size_t)(b * NKV + kv)) * HD * SEQL + tt * 64;
    int tid = threadIdx.x;
    for (int i = tid; i < 1024; i += 256){
        int d = i >> 3, sc = i & 7;
        u16 tmp[8];
        #pragma unroll
        for (int j = 0; j < 8; j++) tmp[j] = src[(size_t)(sc * 8 + j) * QKVN + d];
        *(uint4*)(dst + (size_t)d * SEQL + sc * 8) = *(const uint4*)tmp;
    }
}

// ---------------- Flash attention v5: double-buffered DMA K/V pipeline ----------------
__global__ __launch_bounds__(256) void attn_kernel(const u16* __restrict__ qkv,
                                                   const u16* __restrict__ Vt,
                                                   u16* __restrict__ outb){
    __shared__ __align__(16) u16 Ks[2][64*128];
    __shared__ __align__(16) u16 Vs[2][128*64];
    __shared__ __align__(16) u16 Ps[4][16*QKS];

    int qt = 31 - (blockIdx.x >> 6);     // longest blocks first
    int bh = blockIdx.x & 63;
    int h  = bh & 31;
    int b  = bh >> 5;
    int kvh = h >> 2;
    int tid = threadIdx.x, wave = tid >> 6, lane = tid & 63;
    int quad = lane >> 4, l16 = lane & 15;
    int q0 = qt * 64, qrow = q0 + wave * 16;

    const u16* Qg  = qkv + (size_t)(b * SEQL + qrow + l16) * QKVN + h * HD;
    const u16* Kg0 = qkv + (size_t)(b * SEQL) * QKVN + HIDDEN + kvh * HD;
    const u16* Vg  = Vt + ((size_t)(b * NKV + kvh)) * HD * SEQL;
    u16* Pw = &Ps[wave][0];

    const u16* kg[4]; u16* kd[4];
    const u16* vg[4]; u16* vd[4];
    {
        int r4 = lane >> 4, s16 = lane & 15;
        int r8 = lane >> 3, s8 = lane & 7;
        #pragma unroll
        for (int i = 0; i < 4; i++){
            int lr = wave * 16 + i * 4 + r4;          // K local row 0..63
            int cK = s16 ^ (lr & 15);
            kg[i] = Kg0 + (size_t)lr * QKVN + cK * 8;
            kd[i] = &Ks[0][0] + lr * 128 + s16 * 8;   // = base + lane*16B
            int dr = wave * 32 + i * 8 + r8;          // V dim row 0..127
            int cV = s8 ^ (dr & 7);
            vg[i] = Vg + (size_t)dr * SEQL + cV * 8;
            vd[i] = &Vs[0][0] + dr * 64 + s8 * 8;     // = base + lane*16B
        }
    }

    // prologue: issue tile 0 into buf 0 before doing anything else
    #pragma unroll
    for (int i = 0; i < 4; i++) gload_lds16(kg[i], kd[i]);
    #pragma unroll
    for (int i = 0; i < 4; i++) gload_lds16(vg[i], vd[i]);

    const float scale = 0.08838834764831845f;
    bf16x8 qf[4];
    #pragma unroll
    for (int c = 0; c < 4; c++){
        bf16x8 q = *(const bf16x8*)(Qg + c * 32 + quad * 8);
        #pragma unroll
        for (int e = 0; e < 8; e++){
            float f = bf2f((u16)q[e]) * scale;
            q[e] = (short)f2bf(f);
        }
        qf[c] = q;
    }

    float m_i[4] = {-INFINITY, -INFINITY, -INFINITY, -INFINITY};
    float l_i[4] = {0.f, 0.f, 0.f, 0.f};
    f32x4 Oacc[8];
    #pragma unroll
    for (int t=0;t<8;t++) Oacc[t] = zero4();

    const int nt = qt + 1;
    for (int t = 0; t < nt; ++t){
        int cur = t & 1;
        __syncthreads();
        if (t + 1 < nt){
            int nxt = (t + 1) & 1;
            size_t kOff = (size_t)(t + 1) * 64 * QKVN;
            int vOff = (t + 1) * 64;
            #pragma unroll
            for (int i = 0; i < 4; i++) gload_lds16(kg[i] + kOff, kd[i] + nxt * 8192);
            #pragma unroll
            for (int i = 0; i < 4; i++) gload_lds16(vg[i] + vOff, vd[i] + nxt * 8192);
        }
        const u16* Kc = &Ks[cur][0];
        const u16* Vc = &Vs[cur][0];
        int k0 = t * 64;

        f32x4 st[4];
        #pragma unroll
        for (int s=0;s<4;s++) st[s] = zero4();
        __builtin_amdgcn_s_setprio(1);
        #pragma unroll
        for (int c4 = 0; c4 < 4; c4++){
            int cw = c4 * 4 + quad;
            #pragma unroll
            for (int s = 0; s < 4; s++){
                bf16x8 bk = *(const bf16x8*)(Kc + (s*16 + l16)*128 + (cw ^ l16)*8);
                st[s] = __builtin_amdgcn_mfma_f32_16x16x32_bf16(qf[c4], bk, st[s], 0, 0, 0);
            }
        }
        __builtin_amdgcn_s_setprio(0);

        bool needmask = (k0 + 63 >= qrow);   // wave-uniform
        int row_g = qrow + quad * 4;
        float alpha[4];
        #pragma unroll
        for (int r=0;r<4;r++){
            float mx = m_i[r];
            #pragma unroll
            for (int s=0;s<4;s++){
                float v = st[s][r];
                if (needmask){
                    int col = k0 + s*16 + l16;
                    v = (col <= row_g + r) ? v : -INFINITY;
                }
                st[s][r] = v;
                mx = fmaxf(mx, v);
            }
            #pragma unroll
            for (int m=8;m>=1;m>>=1) mx = fmaxf(mx, __shfl_xor(mx, m));
            float mnew = mx;
            alpha[r] = __expf(m_i[r] - mnew);
            float rs = 0.f;
            #pragma unroll
            for (int s=0;s<4;s++){
                float pv = __expf(st[s][r] - mnew);
                st[s][r] = pv;
                rs += pv;
            }
            #pragma unroll
            for (int m=8;m>=1;m>>=1) rs += __shfl_xor(rs, m);
            l_i[r] = l_i[r] * alpha[r] + rs;
            m_i[r] = mnew;
        }

        #pragma unroll
        for (int s=0;s<8;s++)
            #pragma unroll
            for (int r=0;r<4;r++) Oacc[s][r] *= alpha[r];

        #pragma unroll
        for (int s=0;s<4;s++)
            #pragma unroll
            for (int r=0;r<4;r++)
                Pw[(quad*4 + r)*QKS + s*16 + l16] = f2bf(st[s][r]);

        __builtin_amdgcn_s_setprio(1);
        #pragma unroll
        for (int c2 = 0; c2 < 2; c2++){
            bf16x8 ap = *(const bf16x8*)(Pw + l16*QKS + c2*32 + quad*8);
            int cw = c2 * 4 + quad;
            #pragma unroll
            for (int s = 0; s < 8; s++){
                int d = s*16 + l16;
                bf16x8 bv = *(const bf16x8*)(Vc + d*64 + (cw ^ (l16 & 7))*8);
                Oacc[s] = __builtin_amdgcn_mfma_f32_16x16x32_bf16(ap, bv, Oacc[s], 0, 0, 0);
            }
        }
        __builtin_amdgcn_s_setprio(0);
    }

    float invl[4];
    #pragma unroll
    for (int r=0;r<4;r++) invl[r] = 1.f / l_i[r];
    int row0 = qrow + quad * 4;
    #pragma unroll
    for (int s=0;s<8;s++)
        #pragma unroll
        for (int r=0;r<4;r++){
            size_t o = ((size_t)(b * SEQL + row0 + r)) * HIDDEN + h * HD + s*16 + l16;
            outb[o] = f2bf(Oacc[s][r] * invl[r]);
        }
}

extern "C" void kernel_launch(void* const* d_in, const int* in_sizes, int n_in,
                              void* d_out, int out_size, void* d_ws, size_t ws_size,
                              hipStream_t stream){
    (void)in_sizes; (void)n_in; (void)out_size; (void)ws_size;
    const float* hs  = (const float*)d_in[0];
    const int*   pos = (const int*)d_in[1];
    const float* Wq  = (const float*)d_in[2];
    const float* Wk  = (const float*)d_in[3];
    const float* Wv  = (const float*)d_in[4];
    const float* Wo  = (const float*)d_in[5];
    float* out = (float*)d_out;
    char* ws = (char*)d_ws;

    u16* Xbf  = (u16*)(ws);              // 4096x4096 bf16 ; later reused as attn output
    u16* Wqkv = (u16*)(ws + 33554432);   // 6144x4096 bf16
    u16* Wob  = (u16*)(ws + 83886080);   // 4096x4096 bf16
    u16* QKVb = (u16*)(ws + 117440512);  // 4096x6144 bf16
    u16* Vt   = (u16*)(ws + 167772160);  // [2][8][128][2048] bf16
    u16* attn_bf = Xbf;

    cvt_kernel<<<16384, 256, 0, stream>>>(hs, Xbf, 4194304);
    cvt_kernel<<<16384, 256, 0, stream>>>(Wq, Wqkv, 4194304);
    cvt_kernel<<<4096,  256, 0, stream>>>(Wk, Wqkv + (size_t)4096*4096, 1048576);
    cvt_kernel<<<4096,  256, 0, stream>>>(Wv, Wqkv + (size_t)5120*4096, 1048576);
    cvt_kernel<<<16384, 256, 0, stream>>>(Wo, Wob, 4194304);

    // QKV proj: M=4096, N=6144 -> 32x48 = 1536 tiles of 128^2; 2 blocks/CU -> 512
    // slots -> exactly 3 generations (zero tail). 1536 % 8 == 0 for the XCD swizzle.
    gemm4_bt<1><<<1536, 256, 0, stream>>>(Xbf, Wqkv, QKVb, NTOK, QKVN, HIDDEN);
    rope_kernel<<<40960, 256, 0, stream>>>(QKVb, pos);
    vtrans_kernel<<<512, 256, 0, stream>>>(QKVb, Vt);
    attn_kernel<<<BATCH*NH*(SEQL/64), 256, 0, stream>>>(QKVb, Vt, attn_bf);
    // O proj: M=N=4096 -> 16x16 = 256 tiles of 256^2 (exactly one full generation)
    gemm8_bt<0><<<256, 512, 0, stream>>>(attn_bf, Wob, out, NTOK, HIDDEN, HIDDEN);
}

// Round 5
// 769.876 us; speedup vs baseline: 1.0593x; 1.0593x over previous
//
#include <hip/hip_runtime.h>
#include <cstdint>
#include <cstddef>

typedef unsigned short u16;
typedef short bf16x8 __attribute__((ext_vector_type(8)));
typedef float f32x4 __attribute__((ext_vector_type(4)));

#define HIDDEN 4096
#define NH 32
#define NKV 8
#define HD 128
#define SEQL 2048
#define BATCH 2
#define NTOK (BATCH*SEQL)          /* 4096 tokens */
#define QKVN (HIDDEN + 2*NKV*HD)   /* 6144 */

#define QKS 68    /* padded LDS row stride (u16) for Ps */

__device__ __forceinline__ u16 f2bf(float f){
    unsigned u = __float_as_uint(f);
    u += 0x7FFF + ((u >> 16) & 1);   // RNE
    return (u16)(u >> 16);
}
__device__ __forceinline__ float bf2f(u16 h){
    return __uint_as_float(((unsigned)h) << 16);
}
__device__ __forceinline__ f32x4 zero4(){
    f32x4 z; z[0]=0.f; z[1]=0.f; z[2]=0.f; z[3]=0.f; return z;
}

typedef const unsigned int __attribute__((address_space(1)))* gas1_t;
typedef unsigned int __attribute__((address_space(3)))* las3_t;
__device__ __forceinline__ void gload_lds16(const u16* g, u16* l){
    __builtin_amdgcn_global_load_lds((gas1_t)g, (las3_t)l, 16, 0, 0);
}

// ---------------- f32 -> bf16 conversion (vectorized x4) ----------------
__global__ __launch_bounds__(256) void cvt_kernel(const float* __restrict__ src,
                                                  u16* __restrict__ dst, int n4){
    int i = blockIdx.x * 256 + threadIdx.x;
    if (i < n4){
        float4 v = ((const float4*)src)[i];
        ushort4 o;
        o.x = f2bf(v.x); o.y = f2bf(v.y); o.z = f2bf(v.z); o.w = f2bf(v.w);
        ((ushort4*)dst)[i] = o;
    }
}

// ---------------- GEMM 256x192: zero-tail QKV projection ----------------
// C[m,n] = sum_k A[m,k]*B[n,k]. BM=256, BN=192, BK=64, 8 waves (4Mx2N), 4 phases.
// Grid = 16x32 = 512 blocks = exactly 2 generations at 1 block/CU (zero tail),
// vs 384/256 = 1.5 for 256^2 (33% inflation) and 2x fetch for 128^2 (HBM-bound).
// LDS = 2 buf x (256+192)x64x2B = 112 KiB. Fetch only 1.17x the 256^2 kernel.
// Swizzle: row r, 16B chunk c at slot c^(r&7); DMA dest linear, source pre-swizzled.
// Stage schedule (7 gloads/thread/K-tile): A(t+1) 4 gloads in p0/p1 (dest buf
// dead since tile t-1's last barrier); B(t+2) 3 gloads in p2/p3 (B's only readers
// are p0, two barriers upstream). Tile-top vmcnt(3): B(t+1)'s 3 loads in flight.
__global__ __launch_bounds__(512) void gemm192_bt(const u16* __restrict__ A,
                                                  const u16* __restrict__ B,
                                                  u16* __restrict__ Cp,
                                                  int M, int N, int K){
    // u16 layout per buffer: A[256*64] then B[192*64]; buffer stride 28672 u16
    __shared__ __align__(16) u16 L[2*28672];
    int tid = threadIdx.x;
    int wave = tid >> 6, lane = tid & 63, quad = lane >> 4, l16 = lane & 15;
    int wm = wave >> 1, wn = wave & 1;          // 4 M-rows x 2 N-cols of waves

    // XCD-aware block swizzle (512 % 8 == 0)
    int nwg = gridDim.x;
    int cpx = nwg >> 3;
    int orig = blockIdx.x;
    int wg = (orig & 7) * cpx + (orig >> 3);
    int nbx = N / 192;
    int bx = wg % nbx, by = wg / nbx;
    size_t row0 = (size_t)by * 256, col0 = (size_t)bx * 192;

    // staging: dest chunk (r = tid>>3, s = tid&7) pulls global chunk cc = s^(r&7);
    // sweeps add 64 rows (r&7 invariant).
    int r0 = tid >> 3, cc = (tid & 7) ^ (r0 & 7);
    const u16* aS0 = A + (row0 + r0) * (size_t)K + cc * 8;
    const u16* bS0 = B + (col0 + r0) * (size_t)K + cc * 8;
    u16* ldsd = &L[0] + tid * 8;

    // A: 4 sweeps of 64 rows; B: 3 sweeps. One sweep = 512 thr x 16B = 64 rows.
#define STAGE_A2(bufi, kt, sw0) do {                                                \
        const u16* g_ = aS0 + (size_t)(kt) * 64 + (size_t)((sw0)*64) * K;           \
        u16* d_ = ldsd + (bufi)*28672 + (sw0)*4096;                                 \
        gload_lds16(g_, d_);                                                        \
        gload_lds16(g_ + (size_t)64 * K, d_ + 4096);                                \
    } while(0)
#define STAGE_B2(bufi, kt) do {                                                     \
        const u16* g_ = bS0 + (size_t)(kt) * 64;                                    \
        u16* d_ = ldsd + (bufi)*28672 + 16384;                                      \
        gload_lds16(g_, d_);                                                        \
        gload_lds16(g_ + (size_t)64 * K, d_ + 4096);                                \
    } while(0)
#define STAGE_B1(bufi, kt) do {                                                     \
        const u16* g_ = bS0 + (size_t)(kt) * 64 + (size_t)128 * K;                  \
        u16* d_ = ldsd + (bufi)*28672 + 16384 + 8192;                               \
        gload_lds16(g_, d_);                                                        \
    } while(0)

    const int nt = K >> 6;

    // fragment read swizzle (row&7 == l16&7 for all fragment rows)
    int swz0 = ((0*4 + quad) ^ (l16 & 7)) * 8;
    int swz1 = ((1*4 + quad) ^ (l16 & 7)) * 8;

    f32x4 acc[4][6];
    #pragma unroll
    for (int i=0;i<4;i++)
        #pragma unroll
        for (int j=0;j<6;j++) acc[i][j] = zero4();

    // prologue: B(0) [3], A(0) [4], B(1) [3] -> 10 in flight
    STAGE_B2(0,0); STAGE_B1(0,0);
    STAGE_A2(0,0,0); STAGE_A2(0,0,2);
    STAGE_B2(1,1); STAGE_B1(1,1);

    bf16x8 bF[6][2];
    for (int t = 0; t < nt; ++t){
        if (t < nt - 1) asm volatile("s_waitcnt vmcnt(3)" ::: "memory");
        else            asm volatile("s_waitcnt vmcnt(0)" ::: "memory");
        __builtin_amdgcn_s_barrier();
        const u16* bufA = &L[(t & 1) * 28672];
        const u16* bufB = bufA + 16384;

        #pragma unroll
        for (int p = 0; p < 4; ++p){
            bf16x8 aF[2];
            if (p == 0){
                #pragma unroll
                for (int ni = 0; ni < 6; ++ni){
                    int rb = (wn*96 + ni*16 + l16) * 64;
                    bF[ni][0] = *(const bf16x8*)(bufB + rb + swz0);
                    bF[ni][1] = *(const bf16x8*)(bufB + rb + swz1);
                }
            }
            {
                int ra = (wm*64 + p*16 + l16) * 64;
                aF[0] = *(const bf16x8*)(bufA + ra + swz0);
                aF[1] = *(const bf16x8*)(bufA + ra + swz1);
            }
            if (p == 0){ if (t + 1 < nt) STAGE_A2((t+1)&1, t+1, 0); }
            if (p == 1){ if (t + 1 < nt) STAGE_A2((t+1)&1, t+1, 2); }
            if (p == 2){ if (t + 2 < nt) STAGE_B2(t&1, t+2); }
            if (p == 3){ if (t + 2 < nt) STAGE_B1(t&1, t+2); }

            __builtin_amdgcn_sched_barrier(0);
            __builtin_amdgcn_s_barrier();
            __builtin_amdgcn_sched_barrier(0);
            __builtin_amdgcn_s_setprio(1);
            #pragma unroll
            for (int ni = 0; ni < 6; ++ni){
                acc[p][ni] = __builtin_amdgcn_mfma_f32_16x16x32_bf16(aF[0], bF[ni][0], acc[p][ni], 0, 0, 0);
                acc[p][ni] = __builtin_amdgcn_mfma_f32_16x16x32_bf16(aF[1], bF[ni][1], acc[p][ni], 0, 0, 0);
            }
            __builtin_amdgcn_s_setprio(0);
            __builtin_amdgcn_sched_barrier(0);
            asm volatile("s_waitcnt lgkmcnt(0)" ::: "memory");
            if (p < 3) __builtin_amdgcn_s_barrier();
        }
    }
#undef STAGE_A2
#undef STAGE_B2
#undef STAGE_B1

    #pragma unroll
    for (int mi = 0; mi < 4; ++mi)
        #pragma unroll
        for (int ni = 0; ni < 6; ++ni){
            size_t row = row0 + wm*64 + mi*16 + quad*4;
            size_t col = col0 + wn*96 + ni*16 + l16;
            #pragma unroll
            for (int r = 0; r < 4; ++r)
                Cp[(row + r) * (size_t)N + col] = f2bf(acc[mi][ni][r]);
        }
}

// ---------------- GEMM 256x256 (8-wave, 4-phase): O-projection ----------------
// 256 blocks = exactly one generation at 1 block/CU -> no tail; unchanged.
template<int OUT_BF16>
__global__ __launch_bounds__(512) void gemm8_bt(const u16* __restrict__ A,
                                                const u16* __restrict__ B,
                                                void* __restrict__ Cp,
                                                int M, int N, int K){
    __shared__ __align__(16) u16 L[2][2][256*64];
    int tid = threadIdx.x;
    int wave = tid >> 6, lane = tid & 63, quad = lane >> 4, l16 = lane & 15;
    int wm = wave >> 2, wn = wave & 3;

    int nwg = gridDim.x;
    int cpx = nwg >> 3;
    int orig = blockIdx.x;
    int wg = (orig & 7) * cpx + (orig >> 3);
    int nbx = N >> 8;
    int bx = wg % nbx, by = wg / nbx;
    size_t row0 = (size_t)by * 256, col0 = (size_t)bx * 256;

    int r0 = tid >> 3, cc = (tid & 7) ^ (r0 & 7);
    const u16* aS0 = A + (row0 + r0) * (size_t)K + cc * 8;
    const u16* bS0 = B + (col0 + r0) * (size_t)K + cc * 8;
    u16* ldsd = &L[0][0][0] + tid * 8;

#define STAGE_HALF(mat, half, bufi, kt) do {                                        \
        const u16* g_ = ((mat) ? bS0 : aS0) + (size_t)((half)*128) * K + (size_t)(kt) * 64; \
        u16* d_ = ldsd + (bufi)*32768 + (mat)*16384 + (half)*8192;                  \
        gload_lds16(g_, d_);                                                        \
        gload_lds16(g_ + (size_t)64 * K, d_ + 4096);                                \
    } while(0)

    const int nt = K >> 6;

    int swz0 = ((0*4 + quad) ^ (l16 & 7)) * 8;
    int swz1 = ((1*4 + quad) ^ (l16 & 7)) * 8;

    f32x4 acc[8][4];
    #pragma unroll
    for (int i=0;i<8;i++)
        #pragma unroll
        for (int j=0;j<4;j++) acc[i][j] = zero4();

    STAGE_HALF(1,0,0,0); STAGE_HALF(1,1,0,0);
    STAGE_HALF(0,0,0,0); STAGE_HALF(0,1,0,0);
    STAGE_HALF(1,0,1,1); STAGE_HALF(1,1,1,1);

    bf16x8 bF[4][2];
    for (int t = 0; t < nt; ++t){
        if (t < nt - 1) asm volatile("s_waitcnt vmcnt(4)" ::: "memory");
        else            asm volatile("s_waitcnt vmcnt(0)" ::: "memory");
        __builtin_amdgcn_s_barrier();
        const u16* bufA = &L[t & 1][0][0];
        const u16* bufB = &L[t & 1][1][0];

        #pragma unroll
        for (int p = 0; p < 4; ++p){
            bf16x8 aF[2][2];
            if (p == 0){
                #pragma unroll
                for (int ni = 0; ni < 4; ++ni){
                    int rb = (wn*64 + ni*16 + l16) * 64;
                    bF[ni][0] = *(const bf16x8*)(bufB + rb + swz0);
                    bF[ni][1] = *(const bf16x8*)(bufB + rb + swz1);
                }
            }
            #pragma unroll
            for (int i = 0; i < 2; ++i){
                int ra = (wm*128 + p*32 + i*16 + l16) * 64;
                aF[i][0] = *(const bf16x8*)(bufA + ra + swz0);
                aF[i][1] = *(const bf16x8*)(bufA + ra + swz1);
            }
            if (p == 0){ if (t + 1 < nt) STAGE_HALF(0, 0, (t+1)&1, t+1); }
            if (p == 1){ if (t + 1 < nt) STAGE_HALF(0, 1, (t+1)&1, t+1); }
            if (p == 2){ if (t + 2 < nt) STAGE_HALF(1, 0, t&1, t+2); }
            if (p == 3){ if (t + 2 < nt) STAGE_HALF(1, 1, t&1, t+2); }

            __builtin_amdgcn_sched_barrier(0);
            __builtin_amdgcn_s_barrier();
            __builtin_amdgcn_sched_barrier(0);
            __builtin_amdgcn_s_setprio(1);
            #pragma unroll
            for (int ni = 0; ni < 4; ++ni)
                #pragma unroll
                for (int i = 0; i < 2; ++i){
                    acc[p*2+i][ni] = __builtin_amdgcn_mfma_f32_16x16x32_bf16(aF[i][0], bF[ni][0], acc[p*2+i][ni], 0, 0, 0);
                    acc[p*2+i][ni] = __builtin_amdgcn_mfma_f32_16x16x32_bf16(aF[i][1], bF[ni][1], acc[p*2+i][ni], 0, 0, 0);
                }
            __builtin_amdgcn_s_setprio(0);
            __builtin_amdgcn_sched_barrier(0);
            asm volatile("s_waitcnt lgkmcnt(0)" ::: "memory");
            if (p < 3) __builtin_amdgcn_s_barrier();
        }
    }
#undef STAGE_HALF

    #pragma unroll
    for (int mi = 0; mi < 8; ++mi)
        #pragma unroll
        for (int ni = 0; ni < 4; ++ni){
            size_t row = row0 + wm*128 + mi*16 + quad*4;
            size_t col = col0 + wn*64 + ni*16 + l16;
            #pragma unroll
            for (int r = 0; r < 4; ++r){
                if (OUT_BF16) ((u16*)Cp)[(row + r) * (size_t)N + col] = f2bf(acc[mi][ni][r]);
                else          ((float*)Cp)[(row + r) * (size_t)N + col] = acc[mi][ni][r];
            }
        }
}

// ---------------- RoPE (in-place on QKV, Q+K regions only) ----------------
__global__ __launch_bounds__(256) void rope_kernel(u16* __restrict__ qkv,
                                                   const int* __restrict__ pos_ids){
    int idx = blockIdx.x * 256 + threadIdx.x;
    if (idx < 8388608){
        int tok = idx >> 11;
        int rem = idx & 2047;
        int h = rem >> 6, d = rem & 63;
        size_t base = (size_t)tok * QKVN + h * 128 + d;
        float v1 = bf2f(qkv[base]), v2 = bf2f(qkv[base + 64]);
        float p = (float)pos_ids[tok];
        float invf = exp2f((float)d * -0.2076205059304601f);  // 10000^(-d/64)
        float fr = p * invf;
        float s, c; __sincosf(fr, &s, &c);
        qkv[base]      = f2bf(v1 * c - v2 * s);
        qkv[base + 64] = f2bf(v2 * c + v1 * s);
    } else {
        int i2 = idx - 8388608;
        int tok = i2 >> 9;
        int rem = i2 & 511;
        int kv = rem >> 6, d = rem & 63;
        size_t base = (size_t)tok * QKVN + HIDDEN + kv * 128 + d;
        float v1 = bf2f(qkv[base]), v2 = bf2f(qkv[base + 64]);
        float p = (float)pos_ids[tok];
        float invf = exp2f((float)d * -0.2076205059304601f);
        float fr = p * invf;
        float s, c; __sincosf(fr, &s, &c);
        qkv[base]      = f2bf(v1 * c - v2 * s);
        qkv[base + 64] = f2bf(v2 * c + v1 * s);
    }
}

// ---------------- V transpose: [tok][kv][d] -> Vt[b,kv][d][tok] ----------------
__global__ __launch_bounds__(256) void vtrans_kernel(const u16* __restrict__ qkv,
                                                     u16* __restrict__ Vt){
    int blk = blockIdx.x;            // 512 blocks: (b,kv) x 32 token tiles
    int tt = blk & 31, bkv = blk >> 5;
    int b = bkv >> 3, kv = bkv & 7;
    const u16* src = qkv + (size_t)(b * SEQL + tt * 64) * QKVN + 5120 + kv * HD;
    u16* dst = Vt + ((size_t)(b * NKV + kv)) * HD * SEQL + tt * 64;
    int tid = threadIdx.x;
    for (int i = tid; i < 1024; i += 256){
        int d = i >> 3, sc = i & 7;
        u16 tmp[8];
        #pragma unroll
        for (int j = 0; j < 8; j++) tmp[j] = src[(size_t)(sc * 8 + j) * QKVN + d];
        *(uint4*)(dst + (size_t)d * SEQL + sc * 8) = *(const uint4*)tmp;
    }
}

// ---------------- Flash attention v5: double-buffered DMA K/V pipeline ----------------
__global__ __launch_bounds__(256) void attn_kernel(const u16* __restrict__ qkv,
                                                   const u16* __restrict__ Vt,
                                                   u16* __restrict__ outb){
    __shared__ __align__(16) u16 Ks[2][64*128];
    __shared__ __align__(16) u16 Vs[2][128*64];
    __shared__ __align__(16) u16 Ps[4][16*QKS];

    int qt = 31 - (blockIdx.x >> 6);     // longest blocks first
    int bh = blockIdx.x & 63;
    int h  = bh & 31;
    int b  = bh >> 5;
    int kvh = h >> 2;
    int tid = threadIdx.x, wave = tid >> 6, lane = tid & 63;
    int quad = lane >> 4, l16 = lane & 15;
    int q0 = qt * 64, qrow = q0 + wave * 16;

    const u16* Qg  = qkv + (size_t)(b * SEQL + qrow + l16) * QKVN + h * HD;
    const u16* Kg0 = qkv + (size_t)(b * SEQL) * QKVN + HIDDEN + kvh * HD;
    const u16* Vg  = Vt + ((size_t)(b * NKV + kvh)) * HD * SEQL;
    u16* Pw = &Ps[wave][0];

    const u16* kg[4]; u16* kd[4];
    const u16* vg[4]; u16* vd[4];
    {
        int r4 = lane >> 4, s16 = lane & 15;
        int r8 = lane >> 3, s8 = lane & 7;
        #pragma unroll
        for (int i = 0; i < 4; i++){
            int lr = wave * 16 + i * 4 + r4;          // K local row 0..63
            int cK = s16 ^ (lr & 15);
            kg[i] = Kg0 + (size_t)lr * QKVN + cK * 8;
            kd[i] = &Ks[0][0] + lr * 128 + s16 * 8;   // = base + lane*16B
            int dr = wave * 32 + i * 8 + r8;          // V dim row 0..127
            int cV = s8 ^ (dr & 7);
            vg[i] = Vg + (size_t)dr * SEQL + cV * 8;
            vd[i] = &Vs[0][0] + dr * 64 + s8 * 8;     // = base + lane*16B
        }
    }

    // prologue: issue tile 0 into buf 0 before doing anything else
    #pragma unroll
    for (int i = 0; i < 4; i++) gload_lds16(kg[i], kd[i]);
    #pragma unroll
    for (int i = 0; i < 4; i++) gload_lds16(vg[i], vd[i]);

    const float scale = 0.08838834764831845f;
    bf16x8 qf[4];
    #pragma unroll
    for (int c = 0; c < 4; c++){
        bf16x8 q = *(const bf16x8*)(Qg + c * 32 + quad * 8);
        #pragma unroll
        for (int e = 0; e < 8; e++){
            float f = bf2f((u16)q[e]) * scale;
            q[e] = (short)f2bf(f);
        }
        qf[c] = q;
    }

    float m_i[4] = {-INFINITY, -INFINITY, -INFINITY, -INFINITY};
    float l_i[4] = {0.f, 0.f, 0.f, 0.f};
    f32x4 Oacc[8];
    #pragma unroll
    for (int t=0;t<8;t++) Oacc[t] = zero4();

    const int nt = qt + 1;
    for (int t = 0; t < nt; ++t){
        int cur = t & 1;
        __syncthreads();
        if (t + 1 < nt){
            int nxt = (t + 1) & 1;
            size_t kOff = (size_t)(t + 1) * 64 * QKVN;
            int vOff = (t + 1) * 64;
            #pragma unroll
            for (int i = 0; i < 4; i++) gload_lds16(kg[i] + kOff, kd[i] + nxt * 8192);
            #pragma unroll
            for (int i = 0; i < 4; i++) gload_lds16(vg[i] + vOff, vd[i] + nxt * 8192);
        }
        const u16* Kc = &Ks[cur][0];
        const u16* Vc = &Vs[cur][0];
        int k0 = t * 64;

        f32x4 st[4];
        #pragma unroll
        for (int s=0;s<4;s++) st[s] = zero4();
        __builtin_amdgcn_s_setprio(1);
        #pragma unroll
        for (int c4 = 0; c4 < 4; c4++){
            int cw = c4 * 4 + quad;
            #pragma unroll
            for (int s = 0; s < 4; s++){
                bf16x8 bk = *(const bf16x8*)(Kc + (s*16 + l16)*128 + (cw ^ l16)*8);
                st[s] = __builtin_amdgcn_mfma_f32_16x16x32_bf16(qf[c4], bk, st[s], 0, 0, 0);
            }
        }
        __builtin_amdgcn_s_setprio(0);

        bool needmask = (k0 + 63 >= qrow);   // wave-uniform
        int row_g = qrow + quad * 4;
        float alpha[4];
        #pragma unroll
        for (int r=0;r<4;r++){
            float mx = m_i[r];
            #pragma unroll
            for (int s=0;s<4;s++){
                float v = st[s][r];
                if (needmask){
                    int col = k0 + s*16 + l16;
                    v = (col <= row_g + r) ? v : -INFINITY;
                }
                st[s][r] = v;
                mx = fmaxf(mx, v);
            }
            #pragma unroll
            for (int m=8;m>=1;m>>=1) mx = fmaxf(mx, __shfl_xor(mx, m));
            float mnew = mx;
            alpha[r] = __expf(m_i[r] - mnew);
            float rs = 0.f;
            #pragma unroll
            for (int s=0;s<4;s++){
                float pv = __expf(st[s][r] - mnew);
                st[s][r] = pv;
                rs += pv;
            }
            #pragma unroll
            for (int m=8;m>=1;m>>=1) rs += __shfl_xor(rs, m);
            l_i[r] = l_i[r] * alpha[r] + rs;
            m_i[r] = mnew;
        }

        #pragma unroll
        for (int s=0;s<8;s++)
            #pragma unroll
            for (int r=0;r<4;r++) Oacc[s][r] *= alpha[r];

        #pragma unroll
        for (int s=0;s<4;s++)
            #pragma unroll
            for (int r=0;r<4;r++)
                Pw[(quad*4 + r)*QKS + s*16 + l16] = f2bf(st[s][r]);

        __builtin_amdgcn_s_setprio(1);
        #pragma unroll
        for (int c2 = 0; c2 < 2; c2++){
            bf16x8 ap = *(const bf16x8*)(Pw + l16*QKS + c2*32 + quad*8);
            int cw = c2 * 4 + quad;
            #pragma unroll
            for (int s = 0; s < 8; s++){
                int d = s*16 + l16;
                bf16x8 bv = *(const bf16x8*)(Vc + d*64 + (cw ^ (l16 & 7))*8);
                Oacc[s] = __builtin_amdgcn_mfma_f32_16x16x32_bf16(ap, bv, Oacc[s], 0, 0, 0);
            }
        }
        __builtin_amdgcn_s_setprio(0);
    }

    float invl[4];
    #pragma unroll
    for (int r=0;r<4;r++) invl[r] = 1.f / l_i[r];
    int row0 = qrow + quad * 4;
    #pragma unroll
    for (int s=0;s<8;s++)
        #pragma unroll
        for (int r=0;r<4;r++){
            size_t o = ((size_t)(b * SEQL + row0 + r)) * HIDDEN + h * HD + s*16 + l16;
            outb[o] = f2bf(Oacc[s][r] * invl[r]);
        }
}

extern "C" void kernel_launch(void* const* d_in, const int* in_sizes, int n_in,
                              void* d_out, int out_size, void* d_ws, size_t ws_size,
                              hipStream_t stream){
    (void)in_sizes; (void)n_in; (void)out_size; (void)ws_size;
    const float* hs  = (const float*)d_in[0];
    const int*   pos = (const int*)d_in[1];
    const float* Wq  = (const float*)d_in[2];
    const float* Wk  = (const float*)d_in[3];
    const float* Wv  = (const float*)d_in[4];
    const float* Wo  = (const float*)d_in[5];
    float* out = (float*)d_out;
    char* ws = (char*)d_ws;

    u16* Xbf  = (u16*)(ws);              // 4096x4096 bf16 ; later reused as attn output
    u16* Wqkv = (u16*)(ws + 33554432);   // 6144x4096 bf16
    u16* Wob  = (u16*)(ws + 83886080);   // 4096x4096 bf16
    u16* QKVb = (u16*)(ws + 117440512);  // 4096x6144 bf16
    u16* Vt   = (u16*)(ws + 167772160);  // [2][8][128][2048] bf16
    u16* attn_bf = Xbf;

    cvt_kernel<<<16384, 256, 0, stream>>>(hs, Xbf, 4194304);
    cvt_kernel<<<16384, 256, 0, stream>>>(Wq, Wqkv, 4194304);
    cvt_kernel<<<4096,  256, 0, stream>>>(Wk, Wqkv + (size_t)4096*4096, 1048576);
    cvt_kernel<<<4096,  256, 0, stream>>>(Wv, Wqkv + (size_t)5120*4096, 1048576);
    cvt_kernel<<<16384, 256, 0, stream>>>(Wo, Wob, 4194304);

    // QKV proj: M=4096, N=6144 -> 16x32 = 512 tiles of 256x192 = exactly 2
    // generations at 1 block/CU (zero tail). 512 % 8 == 0 for the XCD swizzle.
    gemm192_bt<<<512, 512, 0, stream>>>(Xbf, Wqkv, QKVb, NTOK, QKVN, HIDDEN);
    rope_kernel<<<40960, 256, 0, stream>>>(QKVb, pos);
    vtrans_kernel<<<512, 256, 0, stream>>>(QKVb, Vt);
    attn_kernel<<<BATCH*NH*(SEQL/64), 256, 0, stream>>>(QKVb, Vt, attn_bf);
    // O proj: M=N=4096 -> 16x16 = 256 tiles of 256^2 (exactly one full generation)
    gemm8_bt<0><<<256, 512, 0, stream>>>(attn_bf, Wob, out, NTOK, HIDDEN, HIDDEN);
}